// Round 25
// baseline (5030.738 us; speedup 1.0000x reference)
//
#include <hip/hip_runtime.h>

#define B_SZ 2048
#define FEAT 840
#define HID  256
#define LAT  128
#define NQ   12
#define NEMB 512

#define T_SUB 40    // 21 tiles x 40 = 840
#define NTILE 21
#define HSTR  46    // h1 row stride (40+2 halo, padded EVEN -> float2 reads align)
#define H2STR 41    // h2 stride ODD -> reducer reads conflict-free (aliased)
#define CHALF 128   // c2 half: h1 slab holds 128 channels at a time
#define HBUF  (CHALF * HSTR)   // 5888 floats; h2 tile (128*41=5248) aliases here

#define W2R_FLOATS ((size_t)HID * 384)   // 98304
#define CBN_FLOATS ((size_t)NQ * NEMB)   // 6144

// numpy pairwise 8-accumulator combine: ((r0+r1)+(r2+r3))+((r4+r5)+(r6+r7))
__device__ __forceinline__ float np8_combine(const float* r) {
    float sA = __fadd_rn(r[0], r[1]);
    float sB = __fadd_rn(r[2], r[3]);
    float sC = __fadd_rn(r[4], r[5]);
    float sD = __fadd_rn(r[6], r[7]);
    return __fadd_rn(__fadd_rn(sA, sB), __fadd_rn(sC, sD));
}

// ---- w2 repack (round-8/10/12 layout): w2r[c2][ly][j*3+k], ly in [0,32) ----
// per-thread slice = 12 consecutive floats, 16B-aligned -> 3x float4 loads
__global__ __launch_bounds__(256) void w2r_kernel(const float* __restrict__ w2,
                                                  float* __restrict__ w2r)
{
    int p = blockIdx.x * 256 + threadIdx.x;          // [0, 256*384)
    if (p >= HID * 384) return;
    int c2 = p / 384, r = p - c2 * 384;
    int ly = r / 12, jk = r - ly * 12;
    int j = jk / 3, k = jk - j * 3;
    w2r[p] = w2[(size_t)(ly*4 + j)*768 + c2*3 + k];
}

// ---- codebook norms, EXACT same c8/np8 op order as the inline rvq path ----
__global__ __launch_bounds__(256) void cbn_kernel(const float* __restrict__ cb,
                                                  float* __restrict__ cbn)
{
    int p = blockIdx.x * 256 + threadIdx.x;          // [0, NQ*NEMB)
    if (p >= NQ * NEMB) return;
    const float* __restrict__ cp = cb + (size_t)p * LAT;
    float c8[8];
#pragma unroll
    for (int j = 0; j < 8; ++j) {
        float c = cp[j];
        c8[j] = __fmul_rn(c, c);
    }
    for (int i = 8; i < LAT; i += 8)
#pragma unroll
        for (int j = 0; j < 8; ++j) {
            float c = cp[i+j];
            c8[j] = __fadd_rn(c8[j], __fmul_rn(c, c));
        }
    cbn[p] = np8_combine(c8);
}

// ---------------- encoder, numpy-f32 bit-faithful ----------------
// FINAL SESSION CHAMPION -- validated 5x: 5058 / 5000 / 4994 / 4792 / 4957
// us (+-3% band, mean ~4960). Baseline 6425 -> ~4960 us (-23%; best 4792),
// absmax 0.0 throughout. Exhausted-lever record (each measured to a
// falsifier):
//  - FMA density: 120 acc/thread optimal (60/72 variants r9/r11/r13 lose).
//  - Load schemes (float4+LDS / float2 / lane-coalesced+uniform-h /
//    s_load+recompute): issue-ratio ~1.7x invariant -> compiler-intrinsic.
//  - Occupancy: register-capped ~2 waves/SIMD; 116 VGPR sits under the 128
//    cliff (r17 unroll4 -> 136 VGPR -> occupancy halved, enc +30%).
//  - Overlap: 2 rows/block + 6 barriers/tile = measured max VALUBusy 77%.
//  - Instruction form: FMA reorder (r19) and packed-pair fp32 (r20) null;
//    codegen not steerable from HIP source. Path past ~45% of the 157 TF
//    scalar-FMA floor would require hand-asm for the conv loop.
// acc carried across halves -> per-(l,t,k) fma chain c2 = 0..255 ascending;
// h2 = relu((k0+k1)+k2+b2); reducer ingests t strictly 0..39: bit-exact.
// (Round-1 lesson: NO min-waves launch-bounds arg.)
template <int USE_WR>
__global__ __launch_bounds__(256) void enc_kernel(
    const float* __restrict__ x,  const float* __restrict__ w1,
    const float* __restrict__ b1, const float* __restrict__ w2,
    const float* __restrict__ w2r,
    const float* __restrict__ b2, float* __restrict__ zout)
{
    __shared__ float xp[2][FEAT + 4];       // 6752 B
    __shared__ float h1s[2][HBUF];          // 47104 B; h2 tiles alias here
    __shared__ float leafs[2][LAT * 8];     // 8192 B   => 62048 B total

    const int tid  = threadIdx.x;           // [0,256)
    const int half = tid >> 7;              // which batch row of the pair
    const int htid = tid & 127;
    const int b    = blockIdx.x * 2 + half;

    const int tx  = htid & 3;               // t-group (10 t's)
    const int ly  = htid >> 2;              // l-group [0,32), 4 l's each
    const int u0  = tx * 10;

    // phase-A mapping: one thread per channel of the half (42 taps each)
    const int ach = htid;

    float* __restrict__ xph = xp[half];
    float* __restrict__ h1h = h1s[half];
    float* __restrict__ lfh = leafs[half];

    float b2v[4];
#pragma unroll
    for (int j = 0; j < 4; ++j) b2v[j] = b2[ly*4 + j];

    for (int i = htid; i < FEAT + 2; i += 128)
        xph[i] = (i >= 1 && i <= FEAT) ? x[(size_t)b*FEAT + i - 1] : 0.f;

    // numpy pairwise-840 leaf state (one l per thread within the half)
    float racc[8];
    int leaf_id = 0, leaf_pos = 0;
#pragma unroll
    for (int j = 0; j < 8; ++j) racc[j] = 0.f;

    __syncthreads();
    for (int t0 = 0; t0 < FEAT; t0 += T_SUB) {
        const bool edge = (t0 == 0) | (t0 + T_SUB == FEAT);

        float sk[4][10][3];
#pragma unroll
        for (int j = 0; j < 4; ++j)
#pragma unroll
            for (int i = 0; i < 10; ++i)
#pragma unroll
                for (int k = 0; k < 3; ++k) sk[j][i][k] = 0.f;

#pragma unroll 1
        for (int hf = 0; hf < 2; ++hf) {
            // ---- phase A (half hf): h1[ach][tp], 42 taps per thread ----
            {
                const int c = hf*CHALF + ach;
                const float wA = w1[c*3+0], wB = w1[c*3+1], wC = w1[c*3+2];
                const float bb = b1[c];
                if (edge) {
                    for (int tp = 0; tp < T_SUB + 2; ++tp) {
                        int tg = t0 - 1 + tp;
                        float v = 0.f;
                        if (tg >= 0 && tg < FEAT) {
                            float s = __fadd_rn(__fadd_rn(__fmul_rn(wA, xph[tg]),
                                                          __fmul_rn(wB, xph[tg+1])),
                                                __fmul_rn(wC, xph[tg+2]));
                            s = __fadd_rn(s, bb);
                            v = s > 0.f ? s : 0.f;
                        }
                        h1h[ach*HSTR + tp] = v;
                    }
                } else {
#pragma unroll 6
                    for (int tp = 0; tp < T_SUB + 2; ++tp) {
                        int tg = t0 - 1 + tp;
                        float s = __fadd_rn(__fadd_rn(__fmul_rn(wA, xph[tg]),
                                                      __fmul_rn(wB, xph[tg+1])),
                                            __fmul_rn(wC, xph[tg+2]));
                        s = __fadd_rn(s, bb);
                        h1h[ach*HSTR + tp] = s > 0.f ? s : 0.f;
                    }
                }
            }
            __syncthreads();

            // ---- phase B (half hf): c2 = hf*128 + cc ascending ----
            if (USE_WR) {
                const float* __restrict__ wbase =
                    w2r + (size_t)(hf*CHALF)*384 + ly*12;
#pragma unroll 2
                for (int cc = 0; cc < CHALF; ++cc) {
                    const float4* __restrict__ wq =
                        (const float4*)(wbase + (size_t)cc*384);
                    float4 A0 = wq[0], A1 = wq[1], A2 = wq[2];
                    float w_[12];
                    w_[0]=A0.x; w_[1]=A0.y; w_[2]=A0.z; w_[3]=A0.w;
                    w_[4]=A1.x; w_[5]=A1.y; w_[6]=A1.z; w_[7]=A1.w;
                    w_[8]=A2.x; w_[9]=A2.y; w_[10]=A2.z; w_[11]=A2.w;

                    const float2* __restrict__ hq =
                        (const float2*)(&h1h[cc*HSTR + u0]);   // even idx: aligned
                    float2 q0=hq[0], q1=hq[1], q2=hq[2], q3=hq[3], q4=hq[4], q5=hq[5];
                    float hv[12] = {q0.x,q0.y,q1.x,q1.y,q2.x,q2.y,
                                    q3.x,q3.y,q4.x,q4.y,q5.x,q5.y};
#pragma unroll
                    for (int j = 0; j < 4; ++j)
#pragma unroll
                        for (int i = 0; i < 10; ++i)
#pragma unroll
                            for (int k = 0; k < 3; ++k)
                                sk[j][i][k] = __fmaf_rn(w_[j*3+k], hv[i+k],
                                                        sk[j][i][k]);
                }
            } else {
                for (int cc = 0; cc < CHALF; ++cc) {
                    int c2 = hf*CHALF + cc;
                    const float* hp = &h1h[cc*HSTR + u0];
                    float hv[12];
#pragma unroll
                    for (int m = 0; m < 12; ++m) hv[m] = hp[m];
#pragma unroll
                    for (int j = 0; j < 4; ++j) {
                        float wa = w2[(size_t)(ly*4+j)*768 + c2*3 + 0];
                        float wb = w2[(size_t)(ly*4+j)*768 + c2*3 + 1];
                        float wc = w2[(size_t)(ly*4+j)*768 + c2*3 + 2];
#pragma unroll
                        for (int i = 0; i < 10; ++i) {
                            sk[j][i][0] = __fmaf_rn(wa, hv[i],   sk[j][i][0]);
                            sk[j][i][1] = __fmaf_rn(wb, hv[i+1], sk[j][i][1]);
                            sk[j][i][2] = __fmaf_rn(wc, hv[i+2], sk[j][i][2]);
                        }
                    }
                }
            }
            __syncthreads();   // h1s reads done before next half / h2 alias
        }

        // h2 = fl(fl(k0+k1)+k2) + b2, relu -> aliased LDS (single stage)
#pragma unroll
        for (int j = 0; j < 4; ++j)
#pragma unroll
            for (int i = 0; i < 10; ++i) {
                float hh = __fadd_rn(__fadd_rn(sk[j][i][0], sk[j][i][1]),
                                     sk[j][i][2]);
                hh = __fadd_rn(hh, b2v[j]);
                hh = hh > 0.f ? hh : 0.f;
                h1h[(ly*4 + j)*H2STR + u0 + i] = hh;
            }
        __syncthreads();

        // reducer: 128 threads of the half ingest t = 0..39 in order
        // (chunked loads of 8 break the latency chain; order sequential)
        for (int g = 0; g < T_SUB; g += 8) {
            float v[8];
#pragma unroll
            for (int m = 0; m < 8; ++m)
                v[m] = h1h[htid*H2STR + g + m];
#pragma unroll
            for (int m = 0; m < 8; ++m) {
                float vv = v[m];
                int j = leaf_pos & 7;
                racc[j] = (leaf_pos < 8) ? vv : __fadd_rn(racc[j], vv);
                ++leaf_pos;
                int llen = (leaf_id == 7) ? 112 : 104;
                if (leaf_pos == llen) {
                    lfh[htid*8 + leaf_id] = np8_combine(racc);
                    ++leaf_id; leaf_pos = 0;
                }
            }
        }
        __syncthreads();   // reducer reads done before next tile's phase A
    }

    // numpy pairwise-840 recombination
    {
        const float* L = &lfh[htid*8];
        float s0 = __fadd_rn(L[0], L[1]);
        float s1 = __fadd_rn(L[2], L[3]);
        float sA = __fadd_rn(s0, s1);
        float s2 = __fadd_rn(L[4], L[5]);
        float s3 = __fadd_rn(L[6], L[7]);
        float sB = __fadd_rn(s2, s3);
        float tot = __fadd_rn(sA, sB);
        zout[(size_t)b*LAT + htid] = __fdiv_rn(tot, 840.0f);
    }
}

// ---------------- RVQ, numpy-f32 bit-faithful ----------------
// Round-16 form (FINAL): parallel 8-chain Ash; float4 dual-code dot loop
// (strict index order per code); 3-stage argmin (256->64->8->1, strict <,
// ascending groups -> numpy first-min preserved).
// USE_CN: codebook norms precomputed by cbn_kernel with the byte-identical
// c8/np8 op sequence -> cn values bit-equal to the inline computation.
template <int USE_CN>
__global__ __launch_bounds__(256) void rvq32_kernel(
    const float* __restrict__ cb, const float* __restrict__ cbn,
    const float* __restrict__ z,
    float* __restrict__ zqout, float* __restrict__ oidx)
{
    __shared__ float rr[LAT];               // 16B-aligned (first decl)
    __shared__ float ash8[8];
    __shared__ float redd[256];
    __shared__ int   rede[256];
    __shared__ float sredd[64];
    __shared__ int   srede[64];
    __shared__ float s8d[8];
    __shared__ int   s8e[8];
    __shared__ int   beste;
    __shared__ float qv[NQ * LAT];

    const int tid = threadIdx.x;
    const int b   = blockIdx.x;

    if (tid < LAT) rr[tid] = z[(size_t)b*LAT + tid];
    __syncthreads();

    for (int q = 0; q < NQ; ++q) {
        const float* __restrict__ cbq = cb + (size_t)q * NEMB * LAT;

        // ---- Ash: 8 parallel chains, exact numpy r8[j] op order ----
        if (tid < 8) {
            float a = __fmul_rn(rr[tid], rr[tid]);
            for (int i = 8; i < LAT; i += 8)
                a = __fadd_rn(a, __fmul_rn(rr[i+tid], rr[i+tid]));
            ash8[tid] = a;
        }
        __syncthreads();
        const float ashv = np8_combine(ash8);   // same combine bits, all threads

        float dmin; int emin;
        if (USE_CN) {
            // two interleaved dot chains, strict index order 0..127 each
            const int e0 = 2*tid;
            const float4* __restrict__ c0 =
                (const float4*)(cbq + (size_t)e0 * LAT);
            const float4* __restrict__ c1 =
                (const float4*)(cbq + (size_t)(e0 + 1) * LAT);
            const float4* __restrict__ r4 = (const float4*)rr;
            float dot0 = 0.f, dot1 = 0.f;
#pragma unroll 8
            for (int m = 0; m < LAT/4; ++m) {
                float4 rv = r4[m];
                float4 av = c0[m];
                float4 bv = c1[m];
                dot0 = __fmaf_rn(av.x, rv.x, dot0);
                dot0 = __fmaf_rn(av.y, rv.y, dot0);
                dot0 = __fmaf_rn(av.z, rv.z, dot0);
                dot0 = __fmaf_rn(av.w, rv.w, dot0);
                dot1 = __fmaf_rn(bv.x, rv.x, dot1);
                dot1 = __fmaf_rn(bv.y, rv.y, dot1);
                dot1 = __fmaf_rn(bv.z, rv.z, dot1);
                dot1 = __fmaf_rn(bv.w, rv.w, dot1);
            }
            float cn0 = cbn[(size_t)q*NEMB + e0];
            float cn1 = cbn[(size_t)q*NEMB + e0 + 1];
            float G0 = __fmul_rn(2.0f, dot0);
            float G1 = __fmul_rn(2.0f, dot1);
            float d0 = __fadd_rn(__fsub_rn(ashv, G0), cn0);
            float d1 = __fadd_rn(__fsub_rn(ashv, G1), cn1);
            dmin = d0; emin = e0;
            if (d1 < dmin) { dmin = d1; emin = e0 + 1; }
        } else {
            dmin = 0.f; emin = 0;
#pragma unroll
            for (int h = 0; h < 2; ++h) {
                int e = 2*tid + h;
                const float* __restrict__ cp = cbq + (size_t)e*LAT;
                float dot = 0.f;
                float c8[8];
#pragma unroll
                for (int j = 0; j < 8; ++j) {
                    float c = cp[j];
                    c8[j] = __fmul_rn(c, c);
                    dot = __fmaf_rn(c, rr[j], dot);
                }
                for (int i = 8; i < LAT; i += 8)
#pragma unroll
                    for (int j = 0; j < 8; ++j) {
                        float c = cp[i+j];
                        dot = __fmaf_rn(c, rr[i+j], dot);
                        c8[j] = __fadd_rn(c8[j], __fmul_rn(c, c));
                    }
                float cn = np8_combine(c8);
                float G  = __fmul_rn(2.0f, dot);
                float d  = __fadd_rn(__fsub_rn(ashv, G), cn);
                if (h == 0) { dmin = d; emin = e; }
                else if (d < dmin) { dmin = d; emin = e; }
            }
        }
        redd[tid] = dmin; rede[tid] = emin;
        __syncthreads();

        // ---- argmin: 256 -> 64 -> 8 -> 1, strict <, ascending groups ----
        if (tid < 64) {
            float bb = redd[tid*4]; int ee = rede[tid*4];
            for (int j = 1; j < 4; ++j) {
                float dj = redd[tid*4 + j];
                if (dj < bb) { bb = dj; ee = rede[tid*4 + j]; }
            }
            sredd[tid] = bb; srede[tid] = ee;
        }
        __syncthreads();
        if (tid < 8) {
            float bb = sredd[tid*8]; int ee = srede[tid*8];
            for (int j = 1; j < 8; ++j) {
                float dj = sredd[tid*8 + j];
                if (dj < bb) { bb = dj; ee = srede[tid*8 + j]; }
            }
            s8d[tid] = bb; s8e[tid] = ee;
        }
        __syncthreads();
        if (tid == 0) {
            float bb = s8d[0]; int ee = s8e[0];
            for (int j = 1; j < 8; ++j) {
                float dj = s8d[j];
                if (dj < bb) { bb = dj; ee = s8e[j]; }
            }
            beste = ee;
            oidx[(size_t)b*NQ + q] = (float)ee;
        }
        __syncthreads();

        if (tid < LAT) {
            float cv = cbq[(size_t)beste*LAT + tid];
            qv[q*LAT + tid] = cv;
            rr[tid] = __fsub_rn(rr[tid], cv);
        }
        __syncthreads();
    }

    if (tid < LAT) {
        float s = qv[tid];
        for (int s2 = 1; s2 < NQ; ++s2)
            s = __fadd_rn(s, qv[s2*LAT + tid]);
        zqout[(size_t)b*LAT + tid] = s;
    }
}

extern "C" void kernel_launch(void* const* d_in, const int* in_sizes, int n_in,
                              void* d_out, int out_size, void* d_ws, size_t ws_size,
                              hipStream_t stream)
{
    (void)in_sizes; (void)n_in; (void)out_size;
    const float* x  = (const float*)d_in[0];
    const float* w1 = (const float*)d_in[1];
    const float* b1 = (const float*)d_in[2];
    const float* w2 = (const float*)d_in[3];
    const float* b2 = (const float*)d_in[4];
    const float* cb = (const float*)d_in[5];

    float* out  = (float*)d_out;
    float* zq   = out;                         // 2048*1*128 floats
    float* oidx = out + (size_t)B_SZ * LAT;    // 2048*1*12 floats

    const size_t w2r_bytes  = W2R_FLOATS * sizeof(float);                 // 393216
    const size_t full_bytes = (W2R_FLOATS + CBN_FLOATS) * sizeof(float);  // 417792

    if (ws_size >= full_bytes) {
        float* w2r = (float*)d_ws;
        float* cbn = (float*)d_ws + W2R_FLOATS;
        w2r_kernel<<<(HID*384 + 255)/256, 256, 0, stream>>>(w2, w2r);
        cbn_kernel<<<(NQ*NEMB + 255)/256, 256, 0, stream>>>(cb, cbn);
        enc_kernel<1><<<B_SZ/2, 256, 0, stream>>>(x, w1, b1, w2, w2r, b2, zq);
        rvq32_kernel<1><<<B_SZ, 256, 0, stream>>>(cb, cbn, zq, zq, oidx);
    } else if (ws_size >= w2r_bytes) {
        float* w2r = (float*)d_ws;
        w2r_kernel<<<(HID*384 + 255)/256, 256, 0, stream>>>(w2, w2r);
        enc_kernel<1><<<B_SZ/2, 256, 0, stream>>>(x, w1, b1, w2, w2r, b2, zq);
        rvq32_kernel<0><<<B_SZ, 256, 0, stream>>>(cb, nullptr, zq, zq, oidx);
    } else {
        enc_kernel<0><<<B_SZ/2, 256, 0, stream>>>(x, w1, b1, w2, nullptr, b2, zq);
        rvq32_kernel<0><<<B_SZ, 256, 0, stream>>>(cb, nullptr, zq, zq, oidx);
    }
}

// Round 26
// 4988.042 us; speedup vs baseline: 1.0086x; 1.0086x over previous
//
#include <hip/hip_runtime.h>

#define B_SZ 2048
#define FEAT 840
#define HID  256
#define LAT  128
#define NQ   12
#define NEMB 512

#define T_SUB 40    // 21 tiles x 40 = 840
#define NTILE 21
#define HSTR  46    // h1 row stride (40+2 halo, padded EVEN -> float2 reads align)
#define H2STR 41    // h2 stride ODD -> reducer reads conflict-free (aliased)
#define CHALF 128   // c2 half: h1 slab holds 128 channels at a time
#define HBUF  (CHALF * HSTR)   // 5888 floats; h2 tile (128*41=5248) aliases here

#define W2R_FLOATS ((size_t)HID * 384)   // 98304
#define CBN_FLOATS ((size_t)NQ * NEMB)   // 6144

// numpy pairwise 8-accumulator combine: ((r0+r1)+(r2+r3))+((r4+r5)+(r6+r7))
__device__ __forceinline__ float np8_combine(const float* r) {
    float sA = __fadd_rn(r[0], r[1]);
    float sB = __fadd_rn(r[2], r[3]);
    float sC = __fadd_rn(r[4], r[5]);
    float sD = __fadd_rn(r[6], r[7]);
    return __fadd_rn(__fadd_rn(sA, sB), __fadd_rn(sC, sD));
}

// ---- w2 repack (round-8/10/12 layout): w2r[c2][ly][j*3+k], ly in [0,32) ----
// per-thread slice = 12 consecutive floats, 16B-aligned -> 3x float4 loads
__global__ __launch_bounds__(256) void w2r_kernel(const float* __restrict__ w2,
                                                  float* __restrict__ w2r)
{
    int p = blockIdx.x * 256 + threadIdx.x;          // [0, 256*384)
    if (p >= HID * 384) return;
    int c2 = p / 384, r = p - c2 * 384;
    int ly = r / 12, jk = r - ly * 12;
    int j = jk / 3, k = jk - j * 3;
    w2r[p] = w2[(size_t)(ly*4 + j)*768 + c2*3 + k];
}

// ---- codebook norms, EXACT same c8/np8 op order as the inline rvq path ----
__global__ __launch_bounds__(256) void cbn_kernel(const float* __restrict__ cb,
                                                  float* __restrict__ cbn)
{
    int p = blockIdx.x * 256 + threadIdx.x;          // [0, NQ*NEMB)
    if (p >= NQ * NEMB) return;
    const float* __restrict__ cp = cb + (size_t)p * LAT;
    float c8[8];
#pragma unroll
    for (int j = 0; j < 8; ++j) {
        float c = cp[j];
        c8[j] = __fmul_rn(c, c);
    }
    for (int i = 8; i < LAT; i += 8)
#pragma unroll
        for (int j = 0; j < 8; ++j) {
            float c = cp[i+j];
            c8[j] = __fadd_rn(c8[j], __fmul_rn(c, c));
        }
    cbn[p] = np8_combine(c8);
}

// ---------------- encoder, numpy-f32 bit-faithful ----------------
// FINAL SESSION CHAMPION -- validated 6x: 5058 / 5000 / 4994 / 4792 / 4957
// / 5031 us (mean 4972, +-3%). Baseline 6425 -> ~4970 us (-23%; best 4792),
// absmax 0.0 throughout. Exhausted-lever record (each measured to a
// falsifier):
//  - FMA density: 120 acc/thread optimal (60/72 variants r9/r11/r13 lose).
//  - Load schemes (float4+LDS / float2 / lane-coalesced+uniform-h /
//    s_load+recompute): issue-ratio ~1.7x invariant -> compiler-intrinsic.
//  - Occupancy: register-capped ~2 waves/SIMD; 116 VGPR sits under the 128
//    cliff (r17 unroll4 -> 136 VGPR -> occupancy halved, enc +30%).
//  - Overlap: 2 rows/block + 6 barriers/tile = measured max VALUBusy 77%.
//  - Instruction form: FMA reorder (r19) and packed-pair fp32 (r20) null;
//    codegen not steerable from HIP source. Path past ~45% of the 157 TF
//    scalar-FMA floor would require hand-asm for the conv loop.
// acc carried across halves -> per-(l,t,k) fma chain c2 = 0..255 ascending;
// h2 = relu((k0+k1)+k2+b2); reducer ingests t strictly 0..39: bit-exact.
// (Round-1 lesson: NO min-waves launch-bounds arg.)
template <int USE_WR>
__global__ __launch_bounds__(256) void enc_kernel(
    const float* __restrict__ x,  const float* __restrict__ w1,
    const float* __restrict__ b1, const float* __restrict__ w2,
    const float* __restrict__ w2r,
    const float* __restrict__ b2, float* __restrict__ zout)
{
    __shared__ float xp[2][FEAT + 4];       // 6752 B
    __shared__ float h1s[2][HBUF];          // 47104 B; h2 tiles alias here
    __shared__ float leafs[2][LAT * 8];     // 8192 B   => 62048 B total

    const int tid  = threadIdx.x;           // [0,256)
    const int half = tid >> 7;              // which batch row of the pair
    const int htid = tid & 127;
    const int b    = blockIdx.x * 2 + half;

    const int tx  = htid & 3;               // t-group (10 t's)
    const int ly  = htid >> 2;              // l-group [0,32), 4 l's each
    const int u0  = tx * 10;

    // phase-A mapping: one thread per channel of the half (42 taps each)
    const int ach = htid;

    float* __restrict__ xph = xp[half];
    float* __restrict__ h1h = h1s[half];
    float* __restrict__ lfh = leafs[half];

    float b2v[4];
#pragma unroll
    for (int j = 0; j < 4; ++j) b2v[j] = b2[ly*4 + j];

    for (int i = htid; i < FEAT + 2; i += 128)
        xph[i] = (i >= 1 && i <= FEAT) ? x[(size_t)b*FEAT + i - 1] : 0.f;

    // numpy pairwise-840 leaf state (one l per thread within the half)
    float racc[8];
    int leaf_id = 0, leaf_pos = 0;
#pragma unroll
    for (int j = 0; j < 8; ++j) racc[j] = 0.f;

    __syncthreads();
    for (int t0 = 0; t0 < FEAT; t0 += T_SUB) {
        const bool edge = (t0 == 0) | (t0 + T_SUB == FEAT);

        float sk[4][10][3];
#pragma unroll
        for (int j = 0; j < 4; ++j)
#pragma unroll
            for (int i = 0; i < 10; ++i)
#pragma unroll
                for (int k = 0; k < 3; ++k) sk[j][i][k] = 0.f;

#pragma unroll 1
        for (int hf = 0; hf < 2; ++hf) {
            // ---- phase A (half hf): h1[ach][tp], 42 taps per thread ----
            {
                const int c = hf*CHALF + ach;
                const float wA = w1[c*3+0], wB = w1[c*3+1], wC = w1[c*3+2];
                const float bb = b1[c];
                if (edge) {
                    for (int tp = 0; tp < T_SUB + 2; ++tp) {
                        int tg = t0 - 1 + tp;
                        float v = 0.f;
                        if (tg >= 0 && tg < FEAT) {
                            float s = __fadd_rn(__fadd_rn(__fmul_rn(wA, xph[tg]),
                                                          __fmul_rn(wB, xph[tg+1])),
                                                __fmul_rn(wC, xph[tg+2]));
                            s = __fadd_rn(s, bb);
                            v = s > 0.f ? s : 0.f;
                        }
                        h1h[ach*HSTR + tp] = v;
                    }
                } else {
#pragma unroll 6
                    for (int tp = 0; tp < T_SUB + 2; ++tp) {
                        int tg = t0 - 1 + tp;
                        float s = __fadd_rn(__fadd_rn(__fmul_rn(wA, xph[tg]),
                                                      __fmul_rn(wB, xph[tg+1])),
                                            __fmul_rn(wC, xph[tg+2]));
                        s = __fadd_rn(s, bb);
                        h1h[ach*HSTR + tp] = s > 0.f ? s : 0.f;
                    }
                }
            }
            __syncthreads();

            // ---- phase B (half hf): c2 = hf*128 + cc ascending ----
            if (USE_WR) {
                const float* __restrict__ wbase =
                    w2r + (size_t)(hf*CHALF)*384 + ly*12;
#pragma unroll 2
                for (int cc = 0; cc < CHALF; ++cc) {
                    const float4* __restrict__ wq =
                        (const float4*)(wbase + (size_t)cc*384);
                    float4 A0 = wq[0], A1 = wq[1], A2 = wq[2];
                    float w_[12];
                    w_[0]=A0.x; w_[1]=A0.y; w_[2]=A0.z; w_[3]=A0.w;
                    w_[4]=A1.x; w_[5]=A1.y; w_[6]=A1.z; w_[7]=A1.w;
                    w_[8]=A2.x; w_[9]=A2.y; w_[10]=A2.z; w_[11]=A2.w;

                    const float2* __restrict__ hq =
                        (const float2*)(&h1h[cc*HSTR + u0]);   // even idx: aligned
                    float2 q0=hq[0], q1=hq[1], q2=hq[2], q3=hq[3], q4=hq[4], q5=hq[5];
                    float hv[12] = {q0.x,q0.y,q1.x,q1.y,q2.x,q2.y,
                                    q3.x,q3.y,q4.x,q4.y,q5.x,q5.y};
#pragma unroll
                    for (int j = 0; j < 4; ++j)
#pragma unroll
                        for (int i = 0; i < 10; ++i)
#pragma unroll
                            for (int k = 0; k < 3; ++k)
                                sk[j][i][k] = __fmaf_rn(w_[j*3+k], hv[i+k],
                                                        sk[j][i][k]);
                }
            } else {
                for (int cc = 0; cc < CHALF; ++cc) {
                    int c2 = hf*CHALF + cc;
                    const float* hp = &h1h[cc*HSTR + u0];
                    float hv[12];
#pragma unroll
                    for (int m = 0; m < 12; ++m) hv[m] = hp[m];
#pragma unroll
                    for (int j = 0; j < 4; ++j) {
                        float wa = w2[(size_t)(ly*4+j)*768 + c2*3 + 0];
                        float wb = w2[(size_t)(ly*4+j)*768 + c2*3 + 1];
                        float wc = w2[(size_t)(ly*4+j)*768 + c2*3 + 2];
#pragma unroll
                        for (int i = 0; i < 10; ++i) {
                            sk[j][i][0] = __fmaf_rn(wa, hv[i],   sk[j][i][0]);
                            sk[j][i][1] = __fmaf_rn(wb, hv[i+1], sk[j][i][1]);
                            sk[j][i][2] = __fmaf_rn(wc, hv[i+2], sk[j][i][2]);
                        }
                    }
                }
            }
            __syncthreads();   // h1s reads done before next half / h2 alias
        }

        // h2 = fl(fl(k0+k1)+k2) + b2, relu -> aliased LDS (single stage)
#pragma unroll
        for (int j = 0; j < 4; ++j)
#pragma unroll
            for (int i = 0; i < 10; ++i) {
                float hh = __fadd_rn(__fadd_rn(sk[j][i][0], sk[j][i][1]),
                                     sk[j][i][2]);
                hh = __fadd_rn(hh, b2v[j]);
                hh = hh > 0.f ? hh : 0.f;
                h1h[(ly*4 + j)*H2STR + u0 + i] = hh;
            }
        __syncthreads();

        // reducer: 128 threads of the half ingest t = 0..39 in order
        // (chunked loads of 8 break the latency chain; order sequential)
        for (int g = 0; g < T_SUB; g += 8) {
            float v[8];
#pragma unroll
            for (int m = 0; m < 8; ++m)
                v[m] = h1h[htid*H2STR + g + m];
#pragma unroll
            for (int m = 0; m < 8; ++m) {
                float vv = v[m];
                int j = leaf_pos & 7;
                racc[j] = (leaf_pos < 8) ? vv : __fadd_rn(racc[j], vv);
                ++leaf_pos;
                int llen = (leaf_id == 7) ? 112 : 104;
                if (leaf_pos == llen) {
                    lfh[htid*8 + leaf_id] = np8_combine(racc);
                    ++leaf_id; leaf_pos = 0;
                }
            }
        }
        __syncthreads();   // reducer reads done before next tile's phase A
    }

    // numpy pairwise-840 recombination
    {
        const float* L = &lfh[htid*8];
        float s0 = __fadd_rn(L[0], L[1]);
        float s1 = __fadd_rn(L[2], L[3]);
        float sA = __fadd_rn(s0, s1);
        float s2 = __fadd_rn(L[4], L[5]);
        float s3 = __fadd_rn(L[6], L[7]);
        float sB = __fadd_rn(s2, s3);
        float tot = __fadd_rn(sA, sB);
        zout[(size_t)b*LAT + htid] = __fdiv_rn(tot, 840.0f);
    }
}

// ---------------- RVQ, numpy-f32 bit-faithful ----------------
// Round-16 form (FINAL): parallel 8-chain Ash; float4 dual-code dot loop
// (strict index order per code); 3-stage argmin (256->64->8->1, strict <,
// ascending groups -> numpy first-min preserved).
// USE_CN: codebook norms precomputed by cbn_kernel with the byte-identical
// c8/np8 op sequence -> cn values bit-equal to the inline computation.
template <int USE_CN>
__global__ __launch_bounds__(256) void rvq32_kernel(
    const float* __restrict__ cb, const float* __restrict__ cbn,
    const float* __restrict__ z,
    float* __restrict__ zqout, float* __restrict__ oidx)
{
    __shared__ float rr[LAT];               // 16B-aligned (first decl)
    __shared__ float ash8[8];
    __shared__ float redd[256];
    __shared__ int   rede[256];
    __shared__ float sredd[64];
    __shared__ int   srede[64];
    __shared__ float s8d[8];
    __shared__ int   s8e[8];
    __shared__ int   beste;
    __shared__ float qv[NQ * LAT];

    const int tid = threadIdx.x;
    const int b   = blockIdx.x;

    if (tid < LAT) rr[tid] = z[(size_t)b*LAT + tid];
    __syncthreads();

    for (int q = 0; q < NQ; ++q) {
        const float* __restrict__ cbq = cb + (size_t)q * NEMB * LAT;

        // ---- Ash: 8 parallel chains, exact numpy r8[j] op order ----
        if (tid < 8) {
            float a = __fmul_rn(rr[tid], rr[tid]);
            for (int i = 8; i < LAT; i += 8)
                a = __fadd_rn(a, __fmul_rn(rr[i+tid], rr[i+tid]));
            ash8[tid] = a;
        }
        __syncthreads();
        const float ashv = np8_combine(ash8);   // same combine bits, all threads

        float dmin; int emin;
        if (USE_CN) {
            // two interleaved dot chains, strict index order 0..127 each
            const int e0 = 2*tid;
            const float4* __restrict__ c0 =
                (const float4*)(cbq + (size_t)e0 * LAT);
            const float4* __restrict__ c1 =
                (const float4*)(cbq + (size_t)(e0 + 1) * LAT);
            const float4* __restrict__ r4 = (const float4*)rr;
            float dot0 = 0.f, dot1 = 0.f;
#pragma unroll 8
            for (int m = 0; m < LAT/4; ++m) {
                float4 rv = r4[m];
                float4 av = c0[m];
                float4 bv = c1[m];
                dot0 = __fmaf_rn(av.x, rv.x, dot0);
                dot0 = __fmaf_rn(av.y, rv.y, dot0);
                dot0 = __fmaf_rn(av.z, rv.z, dot0);
                dot0 = __fmaf_rn(av.w, rv.w, dot0);
                dot1 = __fmaf_rn(bv.x, rv.x, dot1);
                dot1 = __fmaf_rn(bv.y, rv.y, dot1);
                dot1 = __fmaf_rn(bv.z, rv.z, dot1);
                dot1 = __fmaf_rn(bv.w, rv.w, dot1);
            }
            float cn0 = cbn[(size_t)q*NEMB + e0];
            float cn1 = cbn[(size_t)q*NEMB + e0 + 1];
            float G0 = __fmul_rn(2.0f, dot0);
            float G1 = __fmul_rn(2.0f, dot1);
            float d0 = __fadd_rn(__fsub_rn(ashv, G0), cn0);
            float d1 = __fadd_rn(__fsub_rn(ashv, G1), cn1);
            dmin = d0; emin = e0;
            if (d1 < dmin) { dmin = d1; emin = e0 + 1; }
        } else {
            dmin = 0.f; emin = 0;
#pragma unroll
            for (int h = 0; h < 2; ++h) {
                int e = 2*tid + h;
                const float* __restrict__ cp = cbq + (size_t)e*LAT;
                float dot = 0.f;
                float c8[8];
#pragma unroll
                for (int j = 0; j < 8; ++j) {
                    float c = cp[j];
                    c8[j] = __fmul_rn(c, c);
                    dot = __fmaf_rn(c, rr[j], dot);
                }
                for (int i = 8; i < LAT; i += 8)
#pragma unroll
                    for (int j = 0; j < 8; ++j) {
                        float c = cp[i+j];
                        dot = __fmaf_rn(c, rr[i+j], dot);
                        c8[j] = __fadd_rn(c8[j], __fmul_rn(c, c));
                    }
                float cn = np8_combine(c8);
                float G  = __fmul_rn(2.0f, dot);
                float d  = __fadd_rn(__fsub_rn(ashv, G), cn);
                if (h == 0) { dmin = d; emin = e; }
                else if (d < dmin) { dmin = d; emin = e; }
            }
        }
        redd[tid] = dmin; rede[tid] = emin;
        __syncthreads();

        // ---- argmin: 256 -> 64 -> 8 -> 1, strict <, ascending groups ----
        if (tid < 64) {
            float bb = redd[tid*4]; int ee = rede[tid*4];
            for (int j = 1; j < 4; ++j) {
                float dj = redd[tid*4 + j];
                if (dj < bb) { bb = dj; ee = rede[tid*4 + j]; }
            }
            sredd[tid] = bb; srede[tid] = ee;
        }
        __syncthreads();
        if (tid < 8) {
            float bb = sredd[tid*8]; int ee = srede[tid*8];
            for (int j = 1; j < 8; ++j) {
                float dj = sredd[tid*8 + j];
                if (dj < bb) { bb = dj; ee = srede[tid*8 + j]; }
            }
            s8d[tid] = bb; s8e[tid] = ee;
        }
        __syncthreads();
        if (tid == 0) {
            float bb = s8d[0]; int ee = s8e[0];
            for (int j = 1; j < 8; ++j) {
                float dj = s8d[j];
                if (dj < bb) { bb = dj; ee = s8e[j]; }
            }
            beste = ee;
            oidx[(size_t)b*NQ + q] = (float)ee;
        }
        __syncthreads();

        if (tid < LAT) {
            float cv = cbq[(size_t)beste*LAT + tid];
            qv[q*LAT + tid] = cv;
            rr[tid] = __fsub_rn(rr[tid], cv);
        }
        __syncthreads();
    }

    if (tid < LAT) {
        float s = qv[tid];
        for (int s2 = 1; s2 < NQ; ++s2)
            s = __fadd_rn(s, qv[s2*LAT + tid]);
        zqout[(size_t)b*LAT + tid] = s;
    }
}

extern "C" void kernel_launch(void* const* d_in, const int* in_sizes, int n_in,
                              void* d_out, int out_size, void* d_ws, size_t ws_size,
                              hipStream_t stream)
{
    (void)in_sizes; (void)n_in; (void)out_size;
    const float* x  = (const float*)d_in[0];
    const float* w1 = (const float*)d_in[1];
    const float* b1 = (const float*)d_in[2];
    const float* w2 = (const float*)d_in[3];
    const float* b2 = (const float*)d_in[4];
    const float* cb = (const float*)d_in[5];

    float* out  = (float*)d_out;
    float* zq   = out;                         // 2048*1*128 floats
    float* oidx = out + (size_t)B_SZ * LAT;    // 2048*1*12 floats

    const size_t w2r_bytes  = W2R_FLOATS * sizeof(float);                 // 393216
    const size_t full_bytes = (W2R_FLOATS + CBN_FLOATS) * sizeof(float);  // 417792

    if (ws_size >= full_bytes) {
        float* w2r = (float*)d_ws;
        float* cbn = (float*)d_ws + W2R_FLOATS;
        w2r_kernel<<<(HID*384 + 255)/256, 256, 0, stream>>>(w2, w2r);
        cbn_kernel<<<(NQ*NEMB + 255)/256, 256, 0, stream>>>(cb, cbn);
        enc_kernel<1><<<B_SZ/2, 256, 0, stream>>>(x, w1, b1, w2, w2r, b2, zq);
        rvq32_kernel<1><<<B_SZ, 256, 0, stream>>>(cb, cbn, zq, zq, oidx);
    } else if (ws_size >= w2r_bytes) {
        float* w2r = (float*)d_ws;
        w2r_kernel<<<(HID*384 + 255)/256, 256, 0, stream>>>(w2, w2r);
        enc_kernel<1><<<B_SZ/2, 256, 0, stream>>>(x, w1, b1, w2, w2r, b2, zq);
        rvq32_kernel<0><<<B_SZ, 256, 0, stream>>>(cb, nullptr, zq, zq, oidx);
    } else {
        enc_kernel<0><<<B_SZ/2, 256, 0, stream>>>(x, w1, b1, w2, nullptr, b2, zq);
        rvq32_kernel<0><<<B_SZ, 256, 0, stream>>>(cb, nullptr, zq, zq, oidx);
    }
}

// Round 27
// 4692.064 us; speedup vs baseline: 1.0722x; 1.0631x over previous
//
#include <hip/hip_runtime.h>

#define B_SZ 2048
#define FEAT 840
#define HID  256
#define LAT  128
#define NQ   12
#define NEMB 512

#define T_SUB 40    // 21 tiles x 40 = 840
#define NTILE 21
#define HSTR  46    // h1 row stride (40+2 halo, padded EVEN -> float2 reads align)
#define H2STR 41    // h2 stride ODD -> reducer reads conflict-free (aliased)
#define CHALF 128   // c2 half: h1 slab holds 128 channels at a time
#define HBUF  (CHALF * HSTR)   // 5888 floats; h2 tile (128*41=5248) aliases here

#define W2R_FLOATS ((size_t)HID * 384)   // 98304
#define CBN_FLOATS ((size_t)NQ * NEMB)   // 6144

// numpy pairwise 8-accumulator combine: ((r0+r1)+(r2+r3))+((r4+r5)+(r6+r7))
__device__ __forceinline__ float np8_combine(const float* r) {
    float sA = __fadd_rn(r[0], r[1]);
    float sB = __fadd_rn(r[2], r[3]);
    float sC = __fadd_rn(r[4], r[5]);
    float sD = __fadd_rn(r[6], r[7]);
    return __fadd_rn(__fadd_rn(sA, sB), __fadd_rn(sC, sD));
}

// ---- w2 repack (round-8/10/12 layout): w2r[c2][ly][j*3+k], ly in [0,32) ----
// per-thread slice = 12 consecutive floats, 16B-aligned -> 3x float4 loads
__global__ __launch_bounds__(256) void w2r_kernel(const float* __restrict__ w2,
                                                  float* __restrict__ w2r)
{
    int p = blockIdx.x * 256 + threadIdx.x;          // [0, 256*384)
    if (p >= HID * 384) return;
    int c2 = p / 384, r = p - c2 * 384;
    int ly = r / 12, jk = r - ly * 12;
    int j = jk / 3, k = jk - j * 3;
    w2r[p] = w2[(size_t)(ly*4 + j)*768 + c2*3 + k];
}

// ---- codebook norms, EXACT same c8/np8 op order as the inline rvq path ----
__global__ __launch_bounds__(256) void cbn_kernel(const float* __restrict__ cb,
                                                  float* __restrict__ cbn)
{
    int p = blockIdx.x * 256 + threadIdx.x;          // [0, NQ*NEMB)
    if (p >= NQ * NEMB) return;
    const float* __restrict__ cp = cb + (size_t)p * LAT;
    float c8[8];
#pragma unroll
    for (int j = 0; j < 8; ++j) {
        float c = cp[j];
        c8[j] = __fmul_rn(c, c);
    }
    for (int i = 8; i < LAT; i += 8)
#pragma unroll
        for (int j = 0; j < 8; ++j) {
            float c = cp[i+j];
            c8[j] = __fadd_rn(c8[j], __fmul_rn(c, c));
        }
    cbn[p] = np8_combine(c8);
}

// ---------------- encoder, numpy-f32 bit-faithful ----------------
// FINAL SESSION CHAMPION -- validated 7x: 5058 / 5000 / 4994 / 4792 / 4957
// / 5031 / 4988 us (mean 4974, +-3%). Baseline 6425 -> ~4970 us (-23%;
// best 4792), absmax 0.0 throughout. Exhausted-lever record (each measured
// to a falsifier):
//  - FMA density: 120 acc/thread optimal (60/72 variants r9/r11/r13 lose).
//  - Load schemes (float4+LDS / float2 / lane-coalesced+uniform-h /
//    s_load+recompute): issue-ratio ~1.7x invariant -> compiler-intrinsic.
//  - Occupancy: register-capped ~2 waves/SIMD; 116 VGPR sits under the 128
//    cliff (r17 unroll4 -> 136 VGPR -> occupancy halved, enc +30%).
//  - Overlap: 2 rows/block + 6 barriers/tile = measured max VALUBusy 77%.
//  - Instruction form: FMA reorder (r19) and packed-pair fp32 (r20) null;
//    codegen not steerable from HIP source. Path past ~45% of the 157 TF
//    scalar-FMA floor would require hand-asm for the conv loop.
// acc carried across halves -> per-(l,t,k) fma chain c2 = 0..255 ascending;
// h2 = relu((k0+k1)+k2+b2); reducer ingests t strictly 0..39: bit-exact.
// (Round-1 lesson: NO min-waves launch-bounds arg.)
template <int USE_WR>
__global__ __launch_bounds__(256) void enc_kernel(
    const float* __restrict__ x,  const float* __restrict__ w1,
    const float* __restrict__ b1, const float* __restrict__ w2,
    const float* __restrict__ w2r,
    const float* __restrict__ b2, float* __restrict__ zout)
{
    __shared__ float xp[2][FEAT + 4];       // 6752 B
    __shared__ float h1s[2][HBUF];          // 47104 B; h2 tiles alias here
    __shared__ float leafs[2][LAT * 8];     // 8192 B   => 62048 B total

    const int tid  = threadIdx.x;           // [0,256)
    const int half = tid >> 7;              // which batch row of the pair
    const int htid = tid & 127;
    const int b    = blockIdx.x * 2 + half;

    const int tx  = htid & 3;               // t-group (10 t's)
    const int ly  = htid >> 2;              // l-group [0,32), 4 l's each
    const int u0  = tx * 10;

    // phase-A mapping: one thread per channel of the half (42 taps each)
    const int ach = htid;

    float* __restrict__ xph = xp[half];
    float* __restrict__ h1h = h1s[half];
    float* __restrict__ lfh = leafs[half];

    float b2v[4];
#pragma unroll
    for (int j = 0; j < 4; ++j) b2v[j] = b2[ly*4 + j];

    for (int i = htid; i < FEAT + 2; i += 128)
        xph[i] = (i >= 1 && i <= FEAT) ? x[(size_t)b*FEAT + i - 1] : 0.f;

    // numpy pairwise-840 leaf state (one l per thread within the half)
    float racc[8];
    int leaf_id = 0, leaf_pos = 0;
#pragma unroll
    for (int j = 0; j < 8; ++j) racc[j] = 0.f;

    __syncthreads();
    for (int t0 = 0; t0 < FEAT; t0 += T_SUB) {
        const bool edge = (t0 == 0) | (t0 + T_SUB == FEAT);

        float sk[4][10][3];
#pragma unroll
        for (int j = 0; j < 4; ++j)
#pragma unroll
            for (int i = 0; i < 10; ++i)
#pragma unroll
                for (int k = 0; k < 3; ++k) sk[j][i][k] = 0.f;

#pragma unroll 1
        for (int hf = 0; hf < 2; ++hf) {
            // ---- phase A (half hf): h1[ach][tp], 42 taps per thread ----
            {
                const int c = hf*CHALF + ach;
                const float wA = w1[c*3+0], wB = w1[c*3+1], wC = w1[c*3+2];
                const float bb = b1[c];
                if (edge) {
                    for (int tp = 0; tp < T_SUB + 2; ++tp) {
                        int tg = t0 - 1 + tp;
                        float v = 0.f;
                        if (tg >= 0 && tg < FEAT) {
                            float s = __fadd_rn(__fadd_rn(__fmul_rn(wA, xph[tg]),
                                                          __fmul_rn(wB, xph[tg+1])),
                                                __fmul_rn(wC, xph[tg+2]));
                            s = __fadd_rn(s, bb);
                            v = s > 0.f ? s : 0.f;
                        }
                        h1h[ach*HSTR + tp] = v;
                    }
                } else {
#pragma unroll 6
                    for (int tp = 0; tp < T_SUB + 2; ++tp) {
                        int tg = t0 - 1 + tp;
                        float s = __fadd_rn(__fadd_rn(__fmul_rn(wA, xph[tg]),
                                                      __fmul_rn(wB, xph[tg+1])),
                                            __fmul_rn(wC, xph[tg+2]));
                        s = __fadd_rn(s, bb);
                        h1h[ach*HSTR + tp] = s > 0.f ? s : 0.f;
                    }
                }
            }
            __syncthreads();

            // ---- phase B (half hf): c2 = hf*128 + cc ascending ----
            if (USE_WR) {
                const float* __restrict__ wbase =
                    w2r + (size_t)(hf*CHALF)*384 + ly*12;
#pragma unroll 2
                for (int cc = 0; cc < CHALF; ++cc) {
                    const float4* __restrict__ wq =
                        (const float4*)(wbase + (size_t)cc*384);
                    float4 A0 = wq[0], A1 = wq[1], A2 = wq[2];
                    float w_[12];
                    w_[0]=A0.x; w_[1]=A0.y; w_[2]=A0.z; w_[3]=A0.w;
                    w_[4]=A1.x; w_[5]=A1.y; w_[6]=A1.z; w_[7]=A1.w;
                    w_[8]=A2.x; w_[9]=A2.y; w_[10]=A2.z; w_[11]=A2.w;

                    const float2* __restrict__ hq =
                        (const float2*)(&h1h[cc*HSTR + u0]);   // even idx: aligned
                    float2 q0=hq[0], q1=hq[1], q2=hq[2], q3=hq[3], q4=hq[4], q5=hq[5];
                    float hv[12] = {q0.x,q0.y,q1.x,q1.y,q2.x,q2.y,
                                    q3.x,q3.y,q4.x,q4.y,q5.x,q5.y};
#pragma unroll
                    for (int j = 0; j < 4; ++j)
#pragma unroll
                        for (int i = 0; i < 10; ++i)
#pragma unroll
                            for (int k = 0; k < 3; ++k)
                                sk[j][i][k] = __fmaf_rn(w_[j*3+k], hv[i+k],
                                                        sk[j][i][k]);
                }
            } else {
                for (int cc = 0; cc < CHALF; ++cc) {
                    int c2 = hf*CHALF + cc;
                    const float* hp = &h1h[cc*HSTR + u0];
                    float hv[12];
#pragma unroll
                    for (int m = 0; m < 12; ++m) hv[m] = hp[m];
#pragma unroll
                    for (int j = 0; j < 4; ++j) {
                        float wa = w2[(size_t)(ly*4+j)*768 + c2*3 + 0];
                        float wb = w2[(size_t)(ly*4+j)*768 + c2*3 + 1];
                        float wc = w2[(size_t)(ly*4+j)*768 + c2*3 + 2];
#pragma unroll
                        for (int i = 0; i < 10; ++i) {
                            sk[j][i][0] = __fmaf_rn(wa, hv[i],   sk[j][i][0]);
                            sk[j][i][1] = __fmaf_rn(wb, hv[i+1], sk[j][i][1]);
                            sk[j][i][2] = __fmaf_rn(wc, hv[i+2], sk[j][i][2]);
                        }
                    }
                }
            }
            __syncthreads();   // h1s reads done before next half / h2 alias
        }

        // h2 = fl(fl(k0+k1)+k2) + b2, relu -> aliased LDS (single stage)
#pragma unroll
        for (int j = 0; j < 4; ++j)
#pragma unroll
            for (int i = 0; i < 10; ++i) {
                float hh = __fadd_rn(__fadd_rn(sk[j][i][0], sk[j][i][1]),
                                     sk[j][i][2]);
                hh = __fadd_rn(hh, b2v[j]);
                hh = hh > 0.f ? hh : 0.f;
                h1h[(ly*4 + j)*H2STR + u0 + i] = hh;
            }
        __syncthreads();

        // reducer: 128 threads of the half ingest t = 0..39 in order
        // (chunked loads of 8 break the latency chain; order sequential)
        for (int g = 0; g < T_SUB; g += 8) {
            float v[8];
#pragma unroll
            for (int m = 0; m < 8; ++m)
                v[m] = h1h[htid*H2STR + g + m];
#pragma unroll
            for (int m = 0; m < 8; ++m) {
                float vv = v[m];
                int j = leaf_pos & 7;
                racc[j] = (leaf_pos < 8) ? vv : __fadd_rn(racc[j], vv);
                ++leaf_pos;
                int llen = (leaf_id == 7) ? 112 : 104;
                if (leaf_pos == llen) {
                    lfh[htid*8 + leaf_id] = np8_combine(racc);
                    ++leaf_id; leaf_pos = 0;
                }
            }
        }
        __syncthreads();   // reducer reads done before next tile's phase A
    }

    // numpy pairwise-840 recombination
    {
        const float* L = &lfh[htid*8];
        float s0 = __fadd_rn(L[0], L[1]);
        float s1 = __fadd_rn(L[2], L[3]);
        float sA = __fadd_rn(s0, s1);
        float s2 = __fadd_rn(L[4], L[5]);
        float s3 = __fadd_rn(L[6], L[7]);
        float sB = __fadd_rn(s2, s3);
        float tot = __fadd_rn(sA, sB);
        zout[(size_t)b*LAT + htid] = __fdiv_rn(tot, 840.0f);
    }
}

// ---------------- RVQ, numpy-f32 bit-faithful ----------------
// Round-16 form (FINAL): parallel 8-chain Ash; float4 dual-code dot loop
// (strict index order per code); 3-stage argmin (256->64->8->1, strict <,
// ascending groups -> numpy first-min preserved).
// USE_CN: codebook norms precomputed by cbn_kernel with the byte-identical
// c8/np8 op sequence -> cn values bit-equal to the inline computation.
template <int USE_CN>
__global__ __launch_bounds__(256) void rvq32_kernel(
    const float* __restrict__ cb, const float* __restrict__ cbn,
    const float* __restrict__ z,
    float* __restrict__ zqout, float* __restrict__ oidx)
{
    __shared__ float rr[LAT];               // 16B-aligned (first decl)
    __shared__ float ash8[8];
    __shared__ float redd[256];
    __shared__ int   rede[256];
    __shared__ float sredd[64];
    __shared__ int   srede[64];
    __shared__ float s8d[8];
    __shared__ int   s8e[8];
    __shared__ int   beste;
    __shared__ float qv[NQ * LAT];

    const int tid = threadIdx.x;
    const int b   = blockIdx.x;

    if (tid < LAT) rr[tid] = z[(size_t)b*LAT + tid];
    __syncthreads();

    for (int q = 0; q < NQ; ++q) {
        const float* __restrict__ cbq = cb + (size_t)q * NEMB * LAT;

        // ---- Ash: 8 parallel chains, exact numpy r8[j] op order ----
        if (tid < 8) {
            float a = __fmul_rn(rr[tid], rr[tid]);
            for (int i = 8; i < LAT; i += 8)
                a = __fadd_rn(a, __fmul_rn(rr[i+tid], rr[i+tid]));
            ash8[tid] = a;
        }
        __syncthreads();
        const float ashv = np8_combine(ash8);   // same combine bits, all threads

        float dmin; int emin;
        if (USE_CN) {
            // two interleaved dot chains, strict index order 0..127 each
            const int e0 = 2*tid;
            const float4* __restrict__ c0 =
                (const float4*)(cbq + (size_t)e0 * LAT);
            const float4* __restrict__ c1 =
                (const float4*)(cbq + (size_t)(e0 + 1) * LAT);
            const float4* __restrict__ r4 = (const float4*)rr;
            float dot0 = 0.f, dot1 = 0.f;
#pragma unroll 8
            for (int m = 0; m < LAT/4; ++m) {
                float4 rv = r4[m];
                float4 av = c0[m];
                float4 bv = c1[m];
                dot0 = __fmaf_rn(av.x, rv.x, dot0);
                dot0 = __fmaf_rn(av.y, rv.y, dot0);
                dot0 = __fmaf_rn(av.z, rv.z, dot0);
                dot0 = __fmaf_rn(av.w, rv.w, dot0);
                dot1 = __fmaf_rn(bv.x, rv.x, dot1);
                dot1 = __fmaf_rn(bv.y, rv.y, dot1);
                dot1 = __fmaf_rn(bv.z, rv.z, dot1);
                dot1 = __fmaf_rn(bv.w, rv.w, dot1);
            }
            float cn0 = cbn[(size_t)q*NEMB + e0];
            float cn1 = cbn[(size_t)q*NEMB + e0 + 1];
            float G0 = __fmul_rn(2.0f, dot0);
            float G1 = __fmul_rn(2.0f, dot1);
            float d0 = __fadd_rn(__fsub_rn(ashv, G0), cn0);
            float d1 = __fadd_rn(__fsub_rn(ashv, G1), cn1);
            dmin = d0; emin = e0;
            if (d1 < dmin) { dmin = d1; emin = e0 + 1; }
        } else {
            dmin = 0.f; emin = 0;
#pragma unroll
            for (int h = 0; h < 2; ++h) {
                int e = 2*tid + h;
                const float* __restrict__ cp = cbq + (size_t)e*LAT;
                float dot = 0.f;
                float c8[8];
#pragma unroll
                for (int j = 0; j < 8; ++j) {
                    float c = cp[j];
                    c8[j] = __fmul_rn(c, c);
                    dot = __fmaf_rn(c, rr[j], dot);
                }
                for (int i = 8; i < LAT; i += 8)
#pragma unroll
                    for (int j = 0; j < 8; ++j) {
                        float c = cp[i+j];
                        dot = __fmaf_rn(c, rr[i+j], dot);
                        c8[j] = __fadd_rn(c8[j], __fmul_rn(c, c));
                    }
                float cn = np8_combine(c8);
                float G  = __fmul_rn(2.0f, dot);
                float d  = __fadd_rn(__fsub_rn(ashv, G), cn);
                if (h == 0) { dmin = d; emin = e; }
                else if (d < dmin) { dmin = d; emin = e; }
            }
        }
        redd[tid] = dmin; rede[tid] = emin;
        __syncthreads();

        // ---- argmin: 256 -> 64 -> 8 -> 1, strict <, ascending groups ----
        if (tid < 64) {
            float bb = redd[tid*4]; int ee = rede[tid*4];
            for (int j = 1; j < 4; ++j) {
                float dj = redd[tid*4 + j];
                if (dj < bb) { bb = dj; ee = rede[tid*4 + j]; }
            }
            sredd[tid] = bb; srede[tid] = ee;
        }
        __syncthreads();
        if (tid < 8) {
            float bb = sredd[tid*8]; int ee = srede[tid*8];
            for (int j = 1; j < 8; ++j) {
                float dj = sredd[tid*8 + j];
                if (dj < bb) { bb = dj; ee = srede[tid*8 + j]; }
            }
            s8d[tid] = bb; s8e[tid] = ee;
        }
        __syncthreads();
        if (tid == 0) {
            float bb = s8d[0]; int ee = s8e[0];
            for (int j = 1; j < 8; ++j) {
                float dj = s8d[j];
                if (dj < bb) { bb = dj; ee = s8e[j]; }
            }
            beste = ee;
            oidx[(size_t)b*NQ + q] = (float)ee;
        }
        __syncthreads();

        if (tid < LAT) {
            float cv = cbq[(size_t)beste*LAT + tid];
            qv[q*LAT + tid] = cv;
            rr[tid] = __fsub_rn(rr[tid], cv);
        }
        __syncthreads();
    }

    if (tid < LAT) {
        float s = qv[tid];
        for (int s2 = 1; s2 < NQ; ++s2)
            s = __fadd_rn(s, qv[s2*LAT + tid]);
        zqout[(size_t)b*LAT + tid] = s;
    }
}

extern "C" void kernel_launch(void* const* d_in, const int* in_sizes, int n_in,
                              void* d_out, int out_size, void* d_ws, size_t ws_size,
                              hipStream_t stream)
{
    (void)in_sizes; (void)n_in; (void)out_size;
    const float* x  = (const float*)d_in[0];
    const float* w1 = (const float*)d_in[1];
    const float* b1 = (const float*)d_in[2];
    const float* w2 = (const float*)d_in[3];
    const float* b2 = (const float*)d_in[4];
    const float* cb = (const float*)d_in[5];

    float* out  = (float*)d_out;
    float* zq   = out;                         // 2048*1*128 floats
    float* oidx = out + (size_t)B_SZ * LAT;    // 2048*1*12 floats

    const size_t w2r_bytes  = W2R_FLOATS * sizeof(float);                 // 393216
    const size_t full_bytes = (W2R_FLOATS + CBN_FLOATS) * sizeof(float);  // 417792

    if (ws_size >= full_bytes) {
        float* w2r = (float*)d_ws;
        float* cbn = (float*)d_ws + W2R_FLOATS;
        w2r_kernel<<<(HID*384 + 255)/256, 256, 0, stream>>>(w2, w2r);
        cbn_kernel<<<(NQ*NEMB + 255)/256, 256, 0, stream>>>(cb, cbn);
        enc_kernel<1><<<B_SZ/2, 256, 0, stream>>>(x, w1, b1, w2, w2r, b2, zq);
        rvq32_kernel<1><<<B_SZ, 256, 0, stream>>>(cb, cbn, zq, zq, oidx);
    } else if (ws_size >= w2r_bytes) {
        float* w2r = (float*)d_ws;
        w2r_kernel<<<(HID*384 + 255)/256, 256, 0, stream>>>(w2, w2r);
        enc_kernel<1><<<B_SZ/2, 256, 0, stream>>>(x, w1, b1, w2, w2r, b2, zq);
        rvq32_kernel<0><<<B_SZ, 256, 0, stream>>>(cb, nullptr, zq, zq, oidx);
    } else {
        enc_kernel<0><<<B_SZ/2, 256, 0, stream>>>(x, w1, b1, w2, nullptr, b2, zq);
        rvq32_kernel<0><<<B_SZ, 256, 0, stream>>>(cb, nullptr, zq, zq, oidx);
    }
}